// Round 1
// baseline (803.564 us; speedup 1.0000x reference)
//
#include <hip/hip_runtime.h>
#include <math.h>

#define SDIM 32
#define ADIM 8
#define INDIM 40      // SDIM + ADIM
#define HDIM 64
#define TRI 528       // 32*33/2
#define TB 16         // batch rows per block
#define NTHREADS 256

// One block handles TB=16 batch rows.
// LDS budget: x 2560 + W1t 10400 + b1 256 + b2 2112 + h 4096 + t 33792
//           = 53216 B -> 3 blocks/CU (12 waves/CU).
__global__ __launch_bounds__(NTHREADS, 3) void sigma_kernel(
    const float* __restrict__ s, const float* __restrict__ a,
    const float* __restrict__ W1, const float* __restrict__ b1,
    const float* __restrict__ W2, const float* __restrict__ b2,
    float* __restrict__ out)
{
    __shared__ float x_lds[TB][INDIM];        // [row][0..39]
    __shared__ float W1t_lds[INDIM][HDIM + 1]; // transposed, padded (bank-conflict-free)
    __shared__ float b1_lds[HDIM];
    __shared__ float b2_lds[TRI];
    __shared__ float h_lds[TB][HDIM];
    __shared__ float t_lds[TB][TRI];

    const int tid = threadIdx.x;
    const int b0 = blockIdx.x * TB;

    // ---------------- phase 1: stage inputs ----------------
    // s rows: contiguous global -> contiguous LDS rows
    for (int idx = tid; idx < TB * SDIM; idx += NTHREADS) {
        x_lds[idx >> 5][idx & 31] = s[(size_t)b0 * SDIM + idx];
    }
    for (int idx = tid; idx < TB * ADIM; idx += NTHREADS) {
        x_lds[idx >> 3][SDIM + (idx & 7)] = a[(size_t)b0 * ADIM + idx];
    }
    // W1 [64][40] row-major -> W1t_lds[i][c] ; pad 65 => write banks (i+c)%32 distinct
    for (int idx = tid; idx < HDIM * INDIM; idx += NTHREADS) {
        int c = idx / INDIM;
        int i = idx - c * INDIM;
        W1t_lds[i][c] = W1[idx];
    }
    if (tid < HDIM) b1_lds[tid] = b1[tid];
    for (int idx = tid; idx < TRI; idx += NTHREADS) b2_lds[idx] = b2[idx];
    __syncthreads();

    // ---------------- phase 2: h = relu(x @ W1^T + b1) ----------------
    {
        const int c  = tid & 63;          // hidden unit
        const int r0 = (tid >> 6) * 4;    // 4 batch rows per thread, wave-uniform
        float acc[4];
        const float bb = b1_lds[c];
#pragma unroll
        for (int p = 0; p < 4; ++p) acc[p] = bb;
        for (int i = 0; i < INDIM; ++i) {
            const float w = W1t_lds[i][c];      // lanes consecutive -> conflict-free
#pragma unroll
            for (int p = 0; p < 4; ++p)
                acc[p] = fmaf(x_lds[r0 + p][i], w, acc[p]);  // broadcast reads
        }
#pragma unroll
        for (int p = 0; p < 4; ++p)
            h_lds[r0 + p][c] = fmaxf(acc[p], 0.0f);
    }
    __syncthreads();

    // ---------------- phase 3: t = h @ W2^T + b2 ----------------
    {
        const int k0 = tid;
        const int k1 = tid + 256;
        float acc0[TB], acc1[TB];
#pragma unroll
        for (int r = 0; r < TB; ++r) { acc0[r] = 0.0f; acc1[r] = 0.0f; }

        const float4* __restrict__ w2a = reinterpret_cast<const float4*>(W2 + (size_t)k0 * HDIM);
        const float4* __restrict__ w2b = reinterpret_cast<const float4*>(W2 + (size_t)k1 * HDIM);

        for (int cq = 0; cq < HDIM / 4; ++cq) {
            const float4 wa = w2a[cq];
            const float4 wb = w2b[cq];
#pragma unroll
            for (int r = 0; r < TB; ++r) {
                const float4 h4 = *reinterpret_cast<const float4*>(&h_lds[r][cq * 4]); // broadcast
                acc0[r] = fmaf(wa.x, h4.x, acc0[r]);
                acc0[r] = fmaf(wa.y, h4.y, acc0[r]);
                acc0[r] = fmaf(wa.z, h4.z, acc0[r]);
                acc0[r] = fmaf(wa.w, h4.w, acc0[r]);
                acc1[r] = fmaf(wb.x, h4.x, acc1[r]);
                acc1[r] = fmaf(wb.y, h4.y, acc1[r]);
                acc1[r] = fmaf(wb.z, h4.z, acc1[r]);
                acc1[r] = fmaf(wb.w, h4.w, acc1[r]);
            }
        }
        const float ba = b2_lds[k0];
        const float bc = b2_lds[k1];
#pragma unroll
        for (int r = 0; r < TB; ++r) {
            t_lds[r][k0] = acc0[r] + ba;
            t_lds[r][k1] = acc1[r] + bc;
        }
        // tail: k = 512..527 handled by threads 0..15
        if (tid < TRI - 512) {
            const int k2 = 512 + tid;
            float acc2[TB];
#pragma unroll
            for (int r = 0; r < TB; ++r) acc2[r] = 0.0f;
            const float4* __restrict__ w2c = reinterpret_cast<const float4*>(W2 + (size_t)k2 * HDIM);
            for (int cq = 0; cq < HDIM / 4; ++cq) {
                const float4 wc = w2c[cq];
#pragma unroll
                for (int r = 0; r < TB; ++r) {
                    const float4 h4 = *reinterpret_cast<const float4*>(&h_lds[r][cq * 4]);
                    acc2[r] = fmaf(wc.x, h4.x, acc2[r]);
                    acc2[r] = fmaf(wc.y, h4.y, acc2[r]);
                    acc2[r] = fmaf(wc.z, h4.z, acc2[r]);
                    acc2[r] = fmaf(wc.w, h4.w, acc2[r]);
                }
            }
            const float bd = b2_lds[k2];
#pragma unroll
            for (int r = 0; r < TB; ++r) t_lds[r][k2] = acc2[r] + bd;
        }
    }
    __syncthreads();

    // ---------------- phase 4: symmetrize + exp(diag) + coalesced store ----------------
    {
        const int i  = tid >> 3;          // output row within 32x32
        const int j0 = (tid & 7) * 4;     // output col start
        int  idx4[4];
        bool dg[4];
#pragma unroll
        for (int jj = 0; jj < 4; ++jj) {
            const int j  = j0 + jj;
            const int lo = i < j ? i : j;
            const int hi = i < j ? j : i;
            idx4[jj] = lo * (65 - lo) / 2 + (hi - lo);   // triu flat index
            dg[jj]   = (i == j);
        }
        float* __restrict__ outb = out + (size_t)b0 * (SDIM * SDIM);
#pragma unroll
        for (int r = 0; r < TB; ++r) {
            float vv[4];
#pragma unroll
            for (int jj = 0; jj < 4; ++jj) {
                float val = t_lds[r][idx4[jj]];
                if (dg[jj]) val = expf(val);
                vv[jj] = val;
            }
            float4 v;
            v.x = vv[0]; v.y = vv[1]; v.z = vv[2]; v.w = vv[3];
            *reinterpret_cast<float4*>(outb + (size_t)r * (SDIM * SDIM) + tid * 4) = v;
        }
    }
}

extern "C" void kernel_launch(void* const* d_in, const int* in_sizes, int n_in,
                              void* d_out, int out_size, void* d_ws, size_t ws_size,
                              hipStream_t stream) {
    const float* s  = (const float*)d_in[0];
    const float* a  = (const float*)d_in[1];
    const float* W1 = (const float*)d_in[2];
    const float* b1 = (const float*)d_in[3];
    const float* W2 = (const float*)d_in[4];
    const float* b2 = (const float*)d_in[5];
    float* out = (float*)d_out;

    const int batch = in_sizes[0] / SDIM;      // 131072
    const int grid  = batch / TB;              // 8192
    sigma_kernel<<<grid, NTHREADS, 0, stream>>>(s, a, W1, b1, W2, b2, out);
}